// Round 6
// baseline (265.195 us; speedup 1.0000x reference)
//
#include <hip/hip_runtime.h>

#define NPTS 1048576
#define NOUT 128
#define NPAR 64
#define BLOCK 256
#define PPT 4              // points per thread
#define CPB (BLOCK * PPT)  // 1024 points per block
#define STRH 136           // params LDS row stride in bf16 (272 B = 17*16, 16B-aligned rows)

typedef float vf4 __attribute__((ext_vector_type(4)));

__device__ __forceinline__ unsigned short f2bf(float f) {
    unsigned int u = __float_as_uint(f);
    u += 0x7fffu + ((u >> 16) & 1u);   // round-to-nearest-even
    return (unsigned short)(u >> 16);
}

__device__ __forceinline__ void bf2x(unsigned int u, float& lo, float& hi) {
    lo = __uint_as_float(u << 16);
    hi = __uint_as_float(u & 0xffff0000u);
}

__global__ __launch_bounds__(BLOCK, 4)
void kan_kernel(const float* __restrict__ x,
                const float* __restrict__ params,
                float* __restrict__ out) {
    __shared__ unsigned short sH[NPAR * STRH];

    const int tid = threadIdx.x;

    // Stage params [64][128] f32 -> LDS bf16
    {
        const float4* p4 = (const float4*)params;
        #pragma unroll
        for (int g = tid; g < NPAR * (NOUT / 4); g += BLOCK) {
            float4 v = p4[g];
            ushort4 h;
            h.x = f2bf(v.x); h.y = f2bf(v.y); h.z = f2bf(v.z); h.w = f2bf(v.w);
            *(ushort4*)&sH[(g >> 5) * STRH + (g & 31) * 4] = h;
        }
    }

    const int base = blockIdx.x * CPB + tid * PPT;
    const float4 xv = *(const float4*)(x + base);
    float xs[PPT] = {xv.x, xv.y, xv.z, xv.w};

    float b[PPT][4];
    float sil[PPT];
    int   rbase[PPT];

    #pragma unroll
    for (int pp = 0; pp < PPT; ++pp) {
        float xx = xs[pp];
        sil[pp] = xx / (1.0f + __expf(-xx));

        float inr = (xx >= -3.0f && xx < 3.0f) ? 1.0f : 0.0f;
        float u = (xx + 3.0f) * 10.0f;
        int si = (int)u;
        si = si < 0 ? 0 : (si > 59 ? 59 : si);

        float Ki   = -3.0f + 0.1f * (float)si;
        float Kim1 = -3.0f + 0.1f * (float)(si - 1 > 0 ? si - 1 : 0);
        float Kim2 = -3.0f + 0.1f * (float)(si - 2 > 0 ? si - 2 : 0);
        float Kip1 = -3.0f + 0.1f * (float)(si + 1);
        float Kip2 = -3.0f + 0.1f * (float)(si + 2 < 60 ? si + 2 : 60);
        float Kip3 = -3.0f + 0.1f * (float)(si + 3 < 60 ? si + 3 : 60);

        float l1 = xx - Ki,   r1 = Kip1 - xx;
        float l2 = xx - Kim1, r2 = Kip2 - xx;
        float l3 = xx - Kim2, r3 = Kip3 - xx;

        float N0 = 1.0f, N1, N2, N3, t, saved;
        t = N0 / (r1 + l1); N0 = r1 * t; N1 = l1 * t;
        t = N0 / (r1 + l2); N0 = r1 * t;          saved = l2 * t;
        t = N1 / (r2 + l1); N1 = saved + r2 * t;  N2    = l1 * t;
        t = N0 / (r1 + l3); N0 = r1 * t;          saved = l3 * t;
        t = N1 / (r2 + l2); N1 = saved + r2 * t;  saved = l2 * t;
        t = N2 / (r3 + l1); N2 = saved + r3 * t;  N3    = l1 * t;

        b[pp][0] = N0 * inr;
        b[pp][1] = N1 * inr;
        b[pp][2] = N2 * inr;
        b[pp][3] = N3 * inr;
        rbase[pp] = si;
    }

    __syncthreads();

    float* outc = out + base;

    float aA[PPT][8], aB[PPT][8];

// Compute one 8-col tile at column J0 into buffer A[PPT][8]
#define COMPUTE(J0, A)                                                         \
    {                                                                          \
        uint4 u63 = *(const uint4*)&sH[63 * STRH + (J0)];                      \
        float p63f[8];                                                         \
        bf2x(u63.x, p63f[0], p63f[1]); bf2x(u63.y, p63f[2], p63f[3]);          \
        bf2x(u63.z, p63f[4], p63f[5]); bf2x(u63.w, p63f[6], p63f[7]);          \
        _Pragma("unroll")                                                      \
        for (int pp = 0; pp < PPT; ++pp) {                                     \
            const unsigned short* rp = &sH[rbase[pp] * STRH + (J0)];           \
            float s = sil[pp];                                                 \
            _Pragma("unroll")                                                  \
            for (int c = 0; c < 8; ++c) A[pp][c] = s * p63f[c];                \
            _Pragma("unroll")                                                  \
            for (int r = 0; r < 4; ++r) {                                      \
                uint4 q = *(const uint4*)(rp + r * STRH);                      \
                float f[8];                                                    \
                bf2x(q.x, f[0], f[1]); bf2x(q.y, f[2], f[3]);                  \
                bf2x(q.z, f[4], f[5]); bf2x(q.w, f[6], f[7]);                  \
                float br = b[pp][r];                                           \
                _Pragma("unroll")                                              \
                for (int c = 0; c < 8; ++c) A[pp][c] = fmaf(br, f[c], A[pp][c]);\
            }                                                                  \
        }                                                                      \
    }

// Issue the 8 transposed float4 stores for tile J0 from buffer A
#define STORE(J0, A)                                                           \
    {                                                                          \
        _Pragma("unroll")                                                      \
        for (int c = 0; c < 8; ++c) {                                          \
            vf4 v = { A[0][c], A[1][c], A[2][c], A[3][c] };                    \
            *(vf4*)(outc + (size_t)((J0) + c) * NPTS) = v;                     \
        }                                                                      \
    }

    // 2-deep store pipeline: each buffer's store->overwrite distance is 2 tiles,
    // so the compiler needs only vmcnt(8), never a full drain, and the HBM
    // write queue stays fed while the next tile's LDS gathers + FMAs run.
    COMPUTE(0, aA);
    int j0 = 0;
    #pragma unroll 1
    for (int t = 0; t < 7; ++t) {
        COMPUTE(j0 + 8, aB);
        STORE(j0, aA);
        COMPUTE(j0 + 16, aA);
        STORE(j0 + 8, aB);
        j0 += 16;
    }
    COMPUTE(120, aB);
    STORE(112, aA);
    STORE(120, aB);

#undef COMPUTE
#undef STORE
}

extern "C" void kernel_launch(void* const* d_in, const int* in_sizes, int n_in,
                              void* d_out, int out_size, void* d_ws, size_t ws_size,
                              hipStream_t stream) {
    const float* x      = (const float*)d_in[0];
    const float* params = (const float*)d_in[1];
    float* out          = (float*)d_out;

    dim3 grid(NPTS / CPB);   // 1024 blocks
    kan_kernel<<<grid, BLOCK, 0, stream>>>(x, params, out);
}

// Round 7
// 126.444 us; speedup vs baseline: 2.0973x; 2.0973x over previous
//
#include <hip/hip_runtime.h>

#define NPTS 1048576
#define NOUT 128
#define NPAR 64
#define BLOCK 256
#define PPT 2              // points per thread (keeps double-buffer live set ~70 VGPR)
#define CPB (BLOCK * PPT)  // 512 points per block
#define STRH 136           // params LDS row stride in bf16 (272 B = 17*16, rows cycle 8 bank groups)

typedef float vf2 __attribute__((ext_vector_type(2)));

__device__ __forceinline__ unsigned short f2bf(float f) {
    unsigned int u = __float_as_uint(f);
    u += 0x7fffu + ((u >> 16) & 1u);   // round-to-nearest-even
    return (unsigned short)(u >> 16);
}

__device__ __forceinline__ void bf2x(unsigned int u, float& lo, float& hi) {
    lo = __uint_as_float(u << 16);
    hi = __uint_as_float(u & 0xffff0000u);
}

__global__ __launch_bounds__(BLOCK, 4)
void kan_kernel(const float* __restrict__ x,
                const float* __restrict__ params,
                float* __restrict__ out) {
    __shared__ unsigned short sH[NPAR * STRH];

    const int tid = threadIdx.x;

    // Stage params [64][128] f32 -> LDS bf16
    {
        const float4* p4 = (const float4*)params;
        #pragma unroll
        for (int g = tid; g < NPAR * (NOUT / 4); g += BLOCK) {
            float4 v = p4[g];
            ushort4 h;
            h.x = f2bf(v.x); h.y = f2bf(v.y); h.z = f2bf(v.z); h.w = f2bf(v.w);
            *(ushort4*)&sH[(g >> 5) * STRH + (g & 31) * 4] = h;
        }
    }

    const int base = blockIdx.x * CPB + tid * PPT;
    const float2 xv = *(const float2*)(x + base);
    float xs[PPT] = {xv.x, xv.y};

    float b[PPT][4];
    float sil[PPT];
    int   rbase[PPT];

    #pragma unroll
    for (int pp = 0; pp < PPT; ++pp) {
        float xx = xs[pp];
        sil[pp] = xx / (1.0f + __expf(-xx));

        float inr = (xx >= -3.0f && xx < 3.0f) ? 1.0f : 0.0f;
        float u = (xx + 3.0f) * 10.0f;
        int si = (int)u;
        si = si < 0 ? 0 : (si > 59 ? 59 : si);

        float Ki   = -3.0f + 0.1f * (float)si;
        float Kim1 = -3.0f + 0.1f * (float)(si - 1 > 0 ? si - 1 : 0);
        float Kim2 = -3.0f + 0.1f * (float)(si - 2 > 0 ? si - 2 : 0);
        float Kip1 = -3.0f + 0.1f * (float)(si + 1);
        float Kip2 = -3.0f + 0.1f * (float)(si + 2 < 60 ? si + 2 : 60);
        float Kip3 = -3.0f + 0.1f * (float)(si + 3 < 60 ? si + 3 : 60);

        float l1 = xx - Ki,   r1 = Kip1 - xx;
        float l2 = xx - Kim1, r2 = Kip2 - xx;
        float l3 = xx - Kim2, r3 = Kip3 - xx;

        float N0 = 1.0f, N1, N2, N3, t, saved;
        t = N0 / (r1 + l1); N0 = r1 * t; N1 = l1 * t;
        t = N0 / (r1 + l2); N0 = r1 * t;          saved = l2 * t;
        t = N1 / (r2 + l1); N1 = saved + r2 * t;  N2    = l1 * t;
        t = N0 / (r1 + l3); N0 = r1 * t;          saved = l3 * t;
        t = N1 / (r2 + l2); N1 = saved + r2 * t;  saved = l2 * t;
        t = N2 / (r3 + l1); N2 = saved + r3 * t;  N3    = l1 * t;

        b[pp][0] = N0 * inr;
        b[pp][1] = N1 * inr;
        b[pp][2] = N2 * inr;
        b[pp][3] = N3 * inr;
        rbase[pp] = si;
    }

    __syncthreads();

    float* outc = out + base;

    // j-phase stagger: wave w of block b starts at tile (w + 4*(b&3)) & 15, so at
    // any instant the chip's store bursts cover all 128 rows (decorrelates the
    // L2-set/slice index, which is identical for addresses 4 MiB apart).
    const int w  = tid >> 6;
    const int st = (w + ((blockIdx.x & 3) << 2)) & 15;

    float bufA[PPT][8], bufB[PPT][8];

// Compute 8-col tile TI (cols TI*8..TI*8+7) into BUF
#define COMPUTE(TI, BUF)                                                       \
    {                                                                          \
        const int j0 = (TI) << 3;                                              \
        uint4 u63 = *(const uint4*)&sH[63 * STRH + j0];                        \
        float p63f[8];                                                         \
        bf2x(u63.x, p63f[0], p63f[1]); bf2x(u63.y, p63f[2], p63f[3]);          \
        bf2x(u63.z, p63f[4], p63f[5]); bf2x(u63.w, p63f[6], p63f[7]);          \
        _Pragma("unroll")                                                      \
        for (int pp = 0; pp < PPT; ++pp) {                                     \
            const unsigned short* rp = &sH[rbase[pp] * STRH + j0];             \
            float s = sil[pp];                                                 \
            _Pragma("unroll")                                                  \
            for (int c = 0; c < 8; ++c) BUF[pp][c] = s * p63f[c];              \
            _Pragma("unroll")                                                  \
            for (int r = 0; r < 4; ++r) {                                      \
                uint4 q = *(const uint4*)(rp + r * STRH);                      \
                float f[8];                                                    \
                bf2x(q.x, f[0], f[1]); bf2x(q.y, f[2], f[3]);                  \
                bf2x(q.z, f[4], f[5]); bf2x(q.w, f[6], f[7]);                  \
                float br = b[pp][r];                                           \
                _Pragma("unroll")                                              \
                for (int c = 0; c < 8; ++c)                                    \
                    BUF[pp][c] = fmaf(br, f[c], BUF[pp][c]);                   \
            }                                                                  \
        }                                                                      \
    }

// Issue the 8 transposed float2 stores for tile TI from BUF
#define STORE(TI, BUF)                                                         \
    {                                                                          \
        float* rowp = outc + (size_t)((TI) << 3) * NPTS;                       \
        _Pragma("unroll")                                                      \
        for (int c = 0; c < 8; ++c) {                                          \
            vf2 v = { BUF[0][c], BUF[1][c] };                                  \
            *(vf2*)(rowp + (size_t)c * NPTS) = v;                              \
        }                                                                      \
    }

    // 2-deep pipeline with one full compute+store of the OTHER buffer between
    // each buffer's store and its overwrite -> compiler needs only vmcnt(8).
    COMPUTE(st, bufA);
    #pragma unroll 1
    for (int k = 0; k < 16; k += 2) {
        const int t0 = (st + k) & 15;
        const int t1 = (st + k + 1) & 15;
        const int t2 = (st + k + 2) & 15;
        STORE(t0, bufA);
        COMPUTE(t1, bufB);
        STORE(t1, bufB);
        if (k < 14) COMPUTE(t2, bufA);
    }

#undef COMPUTE
#undef STORE
}

extern "C" void kernel_launch(void* const* d_in, const int* in_sizes, int n_in,
                              void* d_out, int out_size, void* d_ws, size_t ws_size,
                              hipStream_t stream) {
    const float* x      = (const float*)d_in[0];
    const float* params = (const float*)d_in[1];
    float* out          = (float*)d_out;

    dim3 grid(NPTS / CPB);   // 2048 blocks
    kan_kernel<<<grid, BLOCK, 0, stream>>>(x, params, out);
}